// Round 6
// baseline (85.894 us; speedup 1.0000x reference)
//
#include <hip/hip_runtime.h>
#include <math.h>

#define HH 28
#define WW 28
#define NPIX 784
#define MMAX 785
#define NMAXP 100
#define NTH 1024
#define BCAP 512       // max basins (theory bound: H1 4-conn <= 393)
#define HSZ 2048
#define HMASK 2047
#define ECAP 2048      // deduped basin-pair edges (random ~470); max survivors = HSZ
#define PCAP 512
#define JITER 6        // racy-jump outer iters; each covers >=16x depth, 16^3 > 784
#define NBUCK 2048     // 11-bit weight buckets for the edge sort
// Essential-death sentinel: must stay FINITE after the harness's bf16
// round-trip (FLT_MAX rounds to +inf in bf16 -> inf-inf=NaN). 1e30 is safe.
#define ESS_DEATH 1e30f

template<int N> struct IC { static constexpr int v = N; };

// monotone float<->u32 (totally ordered as unsigned)
__device__ __forceinline__ unsigned f2mono(float f) {
    unsigned u = __float_as_uint(f);
    return (u & 0x80000000u) ? ~u : (u | 0x80000000u);
}
__device__ __forceinline__ float mono2f(unsigned m) {
    unsigned u = (m & 0x80000000u) ? (m ^ 0x80000000u) : ~m;
    return __uint_as_float(u);
}

// neighbors of cell c; nb[k] = -1 if invalid.
// which==0: 8-conn. which==1: 4-conn + virtual boundary node NPIX.
__device__ __forceinline__ int get_nbrs(int c, int which, int* nb) {
    int ci = c / WW;
    int cj = c - ci * WW;
    if (which == 0) {
        const int di[8] = {-1,-1,-1, 0, 0, 1, 1, 1};
        const int dj[8] = {-1, 0, 1,-1, 1,-1, 0, 1};
        #pragma unroll
        for (int k = 0; k < 8; ++k) {
            int ii = ci + di[k], jj = cj + dj[k];
            nb[k] = (ii >= 0 && ii < HH && jj >= 0 && jj < WW) ? (ii * WW + jj) : -1;
        }
        return 8;
    } else {
        const int di[4] = {-1, 1, 0, 0};
        const int dj[4] = { 0, 0,-1, 1};
        #pragma unroll
        for (int k = 0; k < 4; ++k) {
            int ii = ci + di[k], jj = cj + dj[k];
            nb[k] = (ii >= 0 && ii < HH && jj >= 0 && jj < WW) ? (ii * WW + jj) : -1;
        }
        nb[4] = (ci == 0 || ci == HH - 1 || cj == 0 || cj == WW - 1) ? NPIX : -1;
        return 5;
    }
}

// One block per (sample, dim): blk = s*2 + which.
// which==0 -> H0 (8-conn sublevel on x); which==1 -> H1 via superlevel
// (sublevel on -x, 4-conn, virtual -inf boundary node).
__global__ __launch_bounds__(NTH)
void pd_kernel(const float* __restrict__ x, float* __restrict__ out)
{
    const int blk   = blockIdx.x;
    const int s     = blk >> 1;
    const int which = blk & 1;
    const int tid   = threadIdx.x;
    const int lane  = tid & 63;
    const int M     = NPIX + which;

    __shared__ float vals[MMAX];
    __shared__ int   dA[MMAX];                  // descent/root ptr (in-place); later minF/ddp
    __shared__ int   dB[MMAX];                  // cidmap; later dd2 (alive ancestor)
    __shared__ int   cido[MMAX];                // per-cell compact basin id
    __shared__ unsigned long long rootsU[BCAP]; // unsorted (valmono<<32)|cell
    __shared__ unsigned bval[BCAP];             // basin-min valmono per cid (= value rank)
    __shared__ unsigned hpool[2 * HSZ];         // hash key | hash val
    __shared__ unsigned cnt[NBUCK];             // bucket counters (separate; zeroed in B1)
    __shared__ unsigned long long e2[ECAP];     // unsorted edges; then SORTED; then sel keys
    __shared__ unsigned long long e3[ECAP];     // bucket-grouped scratch
    __shared__ unsigned long long mrec[PCAP];   // merge records (wmono<<32)|y (order free)
    __shared__ float pb[PCAP], pdd[PCAP];       // recorded pairs (output space)
    __shared__ int   rsel[NMAXP];               // output slot -> pair index
    __shared__ int   bcnt, scnt, npairs, np0g;
    __shared__ int   jflag[JITER];
    __shared__ int   wtot[NTH / 64];

    unsigned* const hkey = hpool;               // hash: pk+1 (0 = empty)
    unsigned* const hval = hpool + HSZ;         // hash: min weight (monotone u32)

    // rank of ki among arr[0..N) (distinct keys; guarded loads -> no padding
    // required). Chunked: wave loads 64 keys coalesced, broadcasts via
    // readlane (unrolled -> constant lane), counts kjj < ki. No barriers.
    auto rankOf = [&](const unsigned long long* arr, int N,
                      unsigned long long ki) -> int {
        int rk = 0;
        int N64 = (N + 63) & ~63;
        for (int base = 0; base < N64; base += 64) {
            unsigned long long kj = (base + lane < N) ? arr[base + lane] : ~0ull;
            unsigned lo = (unsigned)kj, hi = (unsigned)(kj >> 32);
            #pragma unroll
            for (int t = 0; t < 64; ++t) {
                unsigned jlo = (unsigned)__builtin_amdgcn_readlane((int)lo, t);
                unsigned jhi = (unsigned)__builtin_amdgcn_readlane((int)hi, t);
                unsigned long long kjj = ((unsigned long long)jhi << 32) | jlo;
                rk += (kjj < ki) ? 1 : 0;
            }
        }
        return rk;
    };

    // ---- B1: init everything with no downstream ordering hazards ----
    if (tid == 0) { bcnt = 0; scnt = 0; npairs = 0; np0g = 0; }
    if (tid < JITER) jflag[tid] = 0;
    for (int i = tid; i < HSZ; i += NTH) { hkey[i] = 0u; hval[i] = 0xFFFFFFFFu; }
    for (int i = tid; i < NBUCK; i += NTH) cnt[i] = 0u;
    for (int i = tid; i < NPIX; i += NTH) {
        float v = x[s * NPIX + i];
        vals[i] = which ? -v : v;
    }
    if (tid == 0 && which) vals[NPIX] = -INFINITY;
    __syncthreads();

    // ---- descent (lex-min over {self} U nbrs) + fused root collection ----
    // NTH >= M: exactly one cell per thread.
    unsigned long long rku = 0ull;
    int rc = 0;
    if (tid < M) {
        int i = tid;
        int best = i; float bv = vals[i];
        if (i < NPIX) {
            int nb[8];
            int K = get_nbrs(i, which, nb);
            for (int k = 0; k < K; ++k) {
                int n = nb[k]; if (n < 0) continue;
                float vn = vals[n];
                if (vn < bv || (vn == bv && n < best)) { bv = vn; best = n; }
            }
        }
        dA[i] = best;
        if (best == i) {
            rku = ((unsigned long long)f2mono(vals[i]) << 32) | (unsigned)i;
            rc = 1;
        }
    }
    {   // wave inclusive scan of rc -> one atomic per wave
        int sc = rc;
        #pragma unroll
        for (int d = 1; d < 64; d <<= 1) {
            int up = __shfl_up(sc, d, 64);
            if (lane >= d) sc += up;
        }
        int wtotal = __shfl(sc, 63, 64);
        int base = 0;
        if (lane == 0 && wtotal) base = atomicAdd(&bcnt, wtotal);
        base = __shfl(base, 0, 64);
        int off = base + sc - rc;
        if (rc && off < BCAP) rootsU[off] = rku;
    }
    __syncthreads();

    int B = bcnt; if (B > BCAP) B = BCAP;
    const int B64 = (B + 63) & ~63;

    // ---- pointer jumping: IN-PLACE racy passes (word-atomic LDS; any
    // interleaving stores an ancestor, pointers only move rootward) + one
    // verified pass per outer iter. cid rank-by-count OVERLAPS iter 0's racy
    // region (touches only rootsU/dB/bval - disjoint from dA). ----
    for (int it = 0; it < JITER; ++it) {
        if (tid < M) {
            #pragma unroll
            for (int r = 0; r < 3; ++r) {
                int q = dA[tid]; int r2 = dA[q];
                if (r2 != q) dA[tid] = r2;
            }
        }
        if (it == 0) {
            for (int i = tid; i < B64; i += NTH) {
                unsigned long long ki = rootsU[i];   // i>=B: garbage, discarded
                int rk = rankOf(rootsU, B, ki);
                if (i < B) {
                    dB[(int)(ki & 0xFFFFFFFFull)] = rk;   // cidmap[root cell]
                    bval[rk] = (unsigned)(ki >> 32);
                }
            }
        }
        __syncthreads();
        // verified pass: exit only when a frozen-state pass changes nothing
        bool changed = false;
        if (tid < M) {
            int q = dA[tid]; int r2 = dA[q];
            if (r2 != q) { dA[tid] = r2; changed = true; }
        }
        unsigned long long mk = __ballot(changed);
        if (lane == 0 && mk) jflag[it] = 1;   // benign race: all store 1
        __syncthreads();
        if (!jflag[it]) break;
    }

    // ---- cid assignment ----
    for (int i = tid; i < M; i += NTH) cido[i] = dB[dA[i]];
    __syncthreads();
    // dA/dB dead from here -> reused by round-1 elimination:
    int* const minF = dA;        // [0..255] first-sorted-edge rank per basin
    int* const ddp  = dA + 256;  // [0..255] died-into pointer (identity = alive)
    int* const dd2  = dB;        // [0..255] alive ancestor after chase

    // ---- cross-basin edges -> hash dedup (min weight per basin pair) ----
    for (int c = tid; c < NPIX; c += NTH) {
        float vc = vals[c];
        int bc = cido[c];
        int nb[8];
        int K = get_nbrs(c, which, nb);
        unsigned wm = f2mono(vc);
        for (int k = 0; k < K; ++k) {
            int n = nb[k]; if (n < 0) continue;
            float vn = vals[n];
            if (!(vn < vc || (vn == vc && n < c))) continue;  // emit from higher endpoint
            int bn = cido[n];
            if (bn == bc) continue;
            unsigned c0 = (unsigned)(bc < bn ? bc : bn);
            unsigned c1 = (unsigned)(bc < bn ? bn : bc);
            unsigned pk  = (c0 << 9) | c1;       // cids < 512 -> 18 bits
            unsigned key = pk + 1u;
            unsigned slot = (pk * 0x9E3779B1u) >> 21;  // 11-bit hash
            for (;;) {
                unsigned prev = atomicCAS(&hkey[slot], 0u, key);
                if (prev == 0u || prev == key) { atomicMin(&hval[slot], wm); break; }
                slot = (slot + 1) & HMASK;
            }
        }
    }
    __syncthreads();

    // ---- gather survivors + FUSED bucket count (cnt is separate storage) ----
    {
        unsigned k0 = hkey[tid], k1 = hkey[tid + NTH];
        unsigned v0 = hval[tid], v1 = hval[tid + NTH];
        int c = (k0 ? 1 : 0) + (k1 ? 1 : 0);
        int sc = c;
        #pragma unroll
        for (int d = 1; d < 64; d <<= 1) {
            int up = __shfl_up(sc, d, 64);
            if (lane >= d) sc += up;
        }
        int wtotal = __shfl(sc, 63, 64);
        int base = 0;
        if (lane == 0 && wtotal) base = atomicAdd(&scnt, wtotal);
        base = __shfl(base, 0, 64);
        int p = base + sc - c;
        if (k0) {
            e2[p] = ((unsigned long long)v0 << 18) | (unsigned long long)(k0 - 1u);
            atomicAdd(&cnt[v0 >> 21], 1u); ++p;
        }
        if (k1) {
            e2[p] = ((unsigned long long)v1 << 18) | (unsigned long long)(k1 - 1u);
            atomicAdd(&cnt[v1 >> 21], 1u); ++p;
        }
    }
    __syncthreads();
    const int S = scnt;                          // <= HSZ = ECAP, no overflow
    const int S64 = (S + 63) & ~63;
    const bool doR1 = (B <= 256) && (S > 0);

    // ---- exclusive prefix over NBUCK bins + e2 pad + round-1 array init ----
    {
        for (int i = S + tid; i < S64; i += NTH) e2[i] = ~0ull;  // Kruskal pad
        if (tid < 256) { minF[tid] = 0x7FFFFFFF; ddp[tid] = tid; }
        unsigned c[2]; int loc = 0;
        #pragma unroll
        for (int k2 = 0; k2 < 2; ++k2) { c[k2] = cnt[tid * 2 + k2]; loc += (int)c[k2]; }
        int scan = loc;
        #pragma unroll
        for (int d = 1; d < 64; d <<= 1) {
            int up = __shfl_up(scan, d, 64);
            if (lane >= d) scan += up;
        }
        int wid = tid >> 6;
        if (lane == 63) wtot[wid] = scan;
        __syncthreads();
        int wb = 0;
        for (int w2 = 0; w2 < wid; ++w2) wb += wtot[w2];   // each thread sums prefix
        int ex = wb + (scan - loc);
        #pragma unroll
        for (int k2 = 0; k2 < 2; ++k2) { cnt[tid * 2 + k2] = (unsigned)ex; ex += (int)c[k2]; }
    }
    __syncthreads();
    // ---- grouped scatter (atomic order; fixed by exact in-bucket rank) ----
    for (int i = tid; i < S; i += NTH) {
        unsigned long long k = e2[i];
        unsigned slot = atomicAdd(&cnt[(unsigned)(k >> 39)], 1u);
        e3[slot] = k;
    }
    __syncthreads();
    // ---- exact in-bucket rank (64-bit keys distinct -> deterministic) +
    //      FUSED round-1 minF (rk IS the sorted index) ----
    for (int i = tid; i < S; i += NTH) {
        unsigned long long ki = e3[i];
        int b = (int)(ki >> 39);
        int lo2 = (b == 0) ? 0 : (int)cnt[b - 1];
        int hi2 = (int)cnt[b];
        int rk = lo2;
        for (int j = lo2; j < hi2; ++j) rk += (e3[j] < ki) ? 1 : 0;
        e2[rk] = ki;
        if (doR1) {
            unsigned pk = (unsigned)ki & 0x3FFFFu;
            atomicMin(&minF[pk >> 9], rk);
            atomicMin(&minF[pk & 511u], rk);
        }
    }
    __syncthreads();

    // ---- ROUND-1 basin elimination (exact, parallel) ----
    // For basin y, its first sorted incident edge e=(y,z,w): if z older (z<y),
    // serial Kruskal provably kills y at e (comp(y)={y} there, since e is y's
    // min edge). Emit pair, mark y died->z. Residual Kruskal replays all edges
    // from pre-merged labels => identical pairing.
    if (doR1) {
        for (int y = tid; y < B; y += NTH) {
            int fi = minF[y];
            if (fi != 0x7FFFFFFF) {
                unsigned long long k = e2[fi];
                unsigned pk = (unsigned)k & 0x3FFFFu;
                int a = (int)(pk >> 9), bq = (int)(pk & 511u);
                int z = (a == y) ? bq : a;
                if (z < y) {   // partner older -> y dies here
                    unsigned wm = (unsigned)(k >> 18);
                    int slot = atomicAdd(&np0g, 1);
                    if (slot < PCAP)
                        mrec[slot] = ((unsigned long long)wm << 32) | (unsigned)y;
                    ddp[y] = z;
                }
            }
        }
    }
    __syncthreads();
    if (doR1) {
        for (int y = tid; y < 256; y += NTH) {   // chase died-into chain to alive root
            int r = ddp[y];
            int r2 = ddp[r];
            while (r2 != r) { r = r2; r2 = ddp[r]; }
            dd2[y] = r;
        }
    }
    __syncthreads();

    // ---- serial Kruskal on wave 0 (reads SORTED e2) ----
    // B <= 256 fast path: labels byte-PACKED, one 32-bit reg/lane
    // (byte j = label of basin j*64+lane), INITIALIZED from round-1 alive
    // ancestors. np starts at round-1's pair count.
    auto kruskalP = [&]() {
        unsigned pl = ((unsigned)dd2[tid]) | ((unsigned)dd2[64 + tid] << 8)
                    | ((unsigned)dd2[128 + tid] << 16) | ((unsigned)dd2[192 + tid] << 24);
        int np = np0g;
        const int target = B - 1;
        for (int base = 0; base < S && np < target; base += 64) {
            unsigned long long ecache = e2[base + tid];      // base mult of 64, tid<64
            unsigned eklo = (unsigned)ecache;
            unsigned ehiw = (unsigned)(ecache >> 32);
            unsigned pkL  = eklo & 0x3FFFFu;
            unsigned raaL = pkL >> 9, rbbL = pkL & 511u;     // < 256 here
            int bpa = __builtin_amdgcn_ds_bpermute((int)((raaL & 63u) << 2), (int)pl);
            int bpb = __builtin_amdgcn_ds_bpermute((int)((rbbL & 63u) << 2), (int)pl);
            unsigned la0 = ((unsigned)bpa >> ((raaL >> 6) * 8)) & 0xFFu;
            unsigned lb0 = ((unsigned)bpb >> ((rbbL >> 6) * 8)) & 0xFFu;
            bool isc = ((base + tid) < S) && (la0 != lb0);
            unsigned long long m = __ballot(isc);
            while (m != 0ull && np < target) {
                unsigned klo[4]; int lnt[4]; unsigned la[4], lb[4]; bool act[4];
                #pragma unroll
                for (int t = 0; t < 4; ++t) {
                    act[t] = (m != 0ull);
                    int ln = act[t] ? (int)__builtin_ctzll(m) : 0;
                    if (act[t]) m &= (m - 1ull);
                    lnt[t] = ln;
                    klo[t] = (unsigned)__builtin_amdgcn_readlane((int)eklo, ln);
                    unsigned pk  = klo[t] & 0x3FFFFu;
                    unsigned raa = pk >> 9, rbb = pk & 511u;  // uniform scalars
                    unsigned kra = (unsigned)__builtin_amdgcn_readlane((int)pl, (int)(raa & 63u));
                    unsigned krb = (unsigned)__builtin_amdgcn_readlane((int)pl, (int)(rbb & 63u));
                    la[t] = (kra >> ((raa >> 6) * 8)) & 0xFFu;   // uniform -> SALU
                    lb[t] = (krb >> ((rbb >> 6) * 8)) & 0xFFu;
                    if (!act[t]) { la[t] = 0; lb[t] = 0; }       // no-op slot
                }
                unsigned ys[4], es[4];
                #pragma unroll
                for (int t = 0; t < 4; ++t) {
                    unsigned A = la[t], Bv = lb[t];
                    #pragma unroll
                    for (int k = 0; k < t; ++k) {
                        A  = (A  == ys[k]) ? es[k] : A;
                        Bv = (Bv == ys[k]) ? es[k] : Bv;
                    }
                    unsigned mn = A < Bv ? A : Bv;
                    unsigned mx = A ^ Bv ^ mn;
                    es[t] = mn;
                    ys[t] = (A != Bv) ? mx : 0xFFFFFFFFu;   // sentinel: no merge
                }
                #pragma unroll
                for (int t = 0; t < 4; ++t) {
                    if (ys[t] != 0xFFFFFFFFu) {
                        unsigned khit = (unsigned)__builtin_amdgcn_readlane(
                            (int)ehiw, lnt[t]);
                        unsigned w = (klo[t] >> 18) | (khit << 14);
                        if (tid == 0 && np < PCAP)
                            mrec[np] = ((unsigned long long)w << 32)
                                     | (unsigned long long)ys[t];
                        ++np;
                        // packed byte replace: bytes of pl equal to y -> e
                        unsigned yr  = ys[t] * 0x01010101u;
                        unsigned xr  = (ys[t] ^ es[t]) * 0x01010101u;
                        unsigned mm  = pl ^ yr;                          // 0-byte = match
                        unsigned nz  = ((mm & 0x7F7F7F7Fu) + 0x7F7F7F7Fu) | mm;
                        unsigned tz  = ~nz & 0x80808080u;                // 0x80 at matches
                        unsigned msk = tz | (tz - (tz >> 7));            // 0xFF at matches
                        pl ^= (xr & msk);
                    }
                }
            }
        }
        if (tid == 0) npairs = (np < PCAP) ? np : PCAP;
    };

    // fallback for 256 < B <= 512: striped labels in 8 regs (no round-1)
    auto kruskal = [&](auto icreg) {
        constexpr int NREG = decltype(icreg)::v;
        int lab[NREG];
        #pragma unroll
        for (int r = 0; r < NREG; ++r) lab[r] = r * 64 + tid;
        int np = 0;
        const int target = B - 1;
        for (int base = 0; base < S && np < target; base += 64) {
            unsigned long long ecache = e2[base + tid];
            unsigned eklo = (unsigned)ecache;
            unsigned ehiw = (unsigned)(ecache >> 32);
            unsigned pkL  = eklo & 0x3FFFFu;
            unsigned raaL = pkL >> 9, rbbL = pkL & 511u;
            int bpa[NREG], bpb[NREG];
            int aA = (int)((raaL & 63u) << 2);
            int aB = (int)((rbbL & 63u) << 2);
            #pragma unroll
            for (int r = 0; r < NREG; ++r) {
                bpa[r] = __builtin_amdgcn_ds_bpermute(aA, lab[r]);
                bpb[r] = __builtin_amdgcn_ds_bpermute(aB, lab[r]);
            }
            int la0, lb0;
            {
                unsigned sA = raaL >> 6, sB = rbbL >> 6;
                int x0 = (sA & 1) ? bpa[1] : bpa[0];
                int x1 = (sA & 1) ? bpa[3] : bpa[2];
                int x2 = (sA & 1) ? bpa[5] : bpa[4];
                int x3 = (sA & 1) ? bpa[7] : bpa[6];
                int x4 = (sA & 2) ? x1 : x0;
                int x5 = (sA & 2) ? x3 : x2;
                la0 = (sA & 4) ? x5 : x4;
                int y0 = (sB & 1) ? bpb[1] : bpb[0];
                int y1 = (sB & 1) ? bpb[3] : bpb[2];
                int y2 = (sB & 1) ? bpb[5] : bpb[4];
                int y3 = (sB & 1) ? bpb[7] : bpb[6];
                int y4 = (sB & 2) ? y1 : y0;
                int y5 = (sB & 2) ? y3 : y2;
                lb0 = (sB & 4) ? y5 : y4;
            }
            bool isc = ((base + tid) < S) && (la0 != lb0);
            unsigned long long m = __ballot(isc);
            while (m != 0ull && np < target) {
                unsigned klo[4]; int lnt[4], la[4], lb[4]; bool act[4];
                #pragma unroll
                for (int t = 0; t < 4; ++t) {
                    act[t] = (m != 0ull);
                    int ln = act[t] ? (int)__builtin_ctzll(m) : 0;
                    if (act[t]) m &= (m - 1ull);
                    lnt[t] = ln;
                    klo[t] = (unsigned)__builtin_amdgcn_readlane((int)eklo, ln);
                    unsigned pk  = klo[t] & 0x3FFFFu;
                    unsigned raa = pk >> 9, rbb = pk & 511u;
                    int sa = (int)(raa >> 6), sb = (int)(rbb >> 6);
                    asm volatile("" : "+v"(sa), "+v"(sb));   // force cndmask tree
                    int a1 = (sa & 1) ? lab[1] : lab[0];
                    int b1 = (sa & 1) ? lab[3] : lab[2];
                    int c1 = (sa & 1) ? lab[5] : lab[4];
                    int d1 = (sa & 1) ? lab[7] : lab[6];
                    int e1 = (sa & 2) ? b1 : a1;
                    int f1 = (sa & 2) ? d1 : c1;
                    int g1 = (sa & 4) ? f1 : e1;
                    int a2 = (sb & 1) ? lab[1] : lab[0];
                    int b2 = (sb & 1) ? lab[3] : lab[2];
                    int c2 = (sb & 1) ? lab[5] : lab[4];
                    int d2 = (sb & 1) ? lab[7] : lab[6];
                    int e2v = (sb & 2) ? b2 : a2;
                    int f2 = (sb & 2) ? d2 : c2;
                    int g2 = (sb & 4) ? f2 : e2v;
                    la[t] = __builtin_amdgcn_readlane(g1, (int)(raa & 63u));
                    lb[t] = __builtin_amdgcn_readlane(g2, (int)(rbb & 63u));
                    if (!act[t]) { la[t] = 0; lb[t] = 0; }
                }
                int ys[4], es[4];
                #pragma unroll
                for (int t = 0; t < 4; ++t) {
                    int A = la[t], Bv = lb[t];
                    #pragma unroll
                    for (int k = 0; k < t; ++k) {
                        A  = (A  == ys[k]) ? es[k] : A;
                        Bv = (Bv == ys[k]) ? es[k] : Bv;
                    }
                    int mn = A < Bv ? A : Bv;
                    int mx = A ^ Bv ^ mn;
                    es[t] = mn;
                    ys[t] = (A != Bv) ? mx : -1;
                }
                #pragma unroll
                for (int t = 0; t < 4; ++t) {
                    if (ys[t] >= 0) {
                        unsigned khit = (unsigned)__builtin_amdgcn_readlane(
                            (int)ehiw, lnt[t]);
                        unsigned w = (klo[t] >> 18) | (khit << 14);
                        if (tid == 0 && np < PCAP)
                            mrec[np] = ((unsigned long long)w << 32) | (unsigned)ys[t];
                        ++np;
                        #pragma unroll
                        for (int r = 0; r < NREG; ++r)
                            lab[r] = (lab[r] == ys[t]) ? es[t] : lab[r];
                    }
                }
            }
        }
        if (tid == 0) npairs = (np < PCAP) ? np : PCAP;
    };

    if (tid < 64 && S > 0) {
        if (B <= 256) kruskalP();
        else          kruskal(IC<8>{});
    }
    __syncthreads();
    const int P = npairs;
    const int P64 = (P + 63) & ~63;

    // ---- materialize pairs + build selection keys (pers desc, idx asc) ----
    for (int i = tid; i < P64; i += NTH) {
        unsigned long long kk2 = ~0ull;
        if (i < P) {
            unsigned long long m = mrec[i];
            int y = (int)(m & 0xFFFFFFFFull);
            float w  = mono2f((unsigned)(m >> 32));
            float bf = mono2f(bval[y]);
            float b, d;
            if (which == 0) { b = bf; d = w; }
            else            { b = -w; d = -bf; }
            pb[i] = b; pdd[i] = d;
            unsigned pm = __float_as_uint(d - b);   // pers > 0 -> monotone bits
            kk2 = ((unsigned long long)(~pm) << 32) | (unsigned)i;
        }
        e2[i] = kk2;
    }
    if (tid < NMAXP) rsel[tid] = -1;
    __syncthreads();

    // ---- top-NMAXP by rank-by-count ----
    const int off = (which == 0) ? 1 : 0;          // H0 slot 0 = essential pair
    for (int i = tid; i < P64; i += NTH) {
        unsigned long long ki = e2[i];
        int rk = rankOf(e2, P64, ki);
        if (i < P && rk < NMAXP - off) rsel[rk + off] = i;
    }
    __syncthreads();

    // ---- write diagram: [32, 2, 100, 2] ----
    float* o = out + (size_t)blk * NMAXP * 2;
    if (tid < NMAXP) {
        float b = 0.f, d = 0.f;
        if (which == 0 && tid == 0) { b = mono2f(bval[0]); d = ESS_DEATH; }
        else {
            int q = rsel[tid];
            if (q >= 0) { b = pb[q]; d = pdd[q]; }
        }
        o[tid * 2]     = b;
        o[tid * 2 + 1] = d;
    }
}

extern "C" void kernel_launch(void* const* d_in, const int* in_sizes, int n_in,
                              void* d_out, int out_size, void* d_ws, size_t ws_size,
                              hipStream_t stream) {
    (void)in_sizes; (void)n_in; (void)out_size; (void)d_ws; (void)ws_size;
    const float* x = (const float*)d_in[0];
    float* out = (float*)d_out;
    pd_kernel<<<dim3(64), dim3(NTH), 0, stream>>>(x, out);
}

// Round 8
// 81.991 us; speedup vs baseline: 1.0476x; 1.0476x over previous
//
#include <hip/hip_runtime.h>
#include <math.h>

#define HH 28
#define WW 28
#define NPIX 784
#define MMAX 785
#define NMAXP 100
#define NTH 1024
#define BCAP 512       // max basins (theory bound: H1 4-conn <= 393)
#define HSZ 2048
#define HMASK 2047
#define ECAP 2048      // deduped basin-pair edges (random ~470); max survivors = HSZ
#define PCAP 512
#define JMAXP 10       // ping-pong doubling passes upper bound (2^10 >= 785)
#define NBUCK 2048     // 11-bit weight buckets for the edge sort
// Essential-death sentinel: must stay FINITE after the harness's bf16
// round-trip (FLT_MAX rounds to +inf in bf16 -> inf-inf=NaN). 1e30 is safe.
#define ESS_DEATH 1e30f

template<int N> struct IC { static constexpr int v = N; };

// monotone float<->u32 (totally ordered as unsigned)
__device__ __forceinline__ unsigned f2mono(float f) {
    unsigned u = __float_as_uint(f);
    return (u & 0x80000000u) ? ~u : (u | 0x80000000u);
}
__device__ __forceinline__ float mono2f(unsigned m) {
    unsigned u = (m & 0x80000000u) ? (m ^ 0x80000000u) : ~m;
    return __uint_as_float(u);
}

// neighbors of cell c; nb[k] = -1 if invalid.
// which==0: 8-conn. which==1: 4-conn + virtual boundary node NPIX.
__device__ __forceinline__ int get_nbrs(int c, int which, int* nb) {
    int ci = c / WW;
    int cj = c - ci * WW;
    if (which == 0) {
        const int di[8] = {-1,-1,-1, 0, 0, 1, 1, 1};
        const int dj[8] = {-1, 0, 1,-1, 1,-1, 0, 1};
        #pragma unroll
        for (int k = 0; k < 8; ++k) {
            int ii = ci + di[k], jj = cj + dj[k];
            nb[k] = (ii >= 0 && ii < HH && jj >= 0 && jj < WW) ? (ii * WW + jj) : -1;
        }
        return 8;
    } else {
        const int di[4] = {-1, 1, 0, 0};
        const int dj[4] = { 0, 0,-1, 1};
        #pragma unroll
        for (int k = 0; k < 4; ++k) {
            int ii = ci + di[k], jj = cj + dj[k];
            nb[k] = (ii >= 0 && ii < HH && jj >= 0 && jj < WW) ? (ii * WW + jj) : -1;
        }
        nb[4] = (ci == 0 || ci == HH - 1 || cj == 0 || cj == WW - 1) ? NPIX : -1;
        return 5;
    }
}

// One block per (sample, dim): blk = s*2 + which.
// which==0 -> H0 (8-conn sublevel on x); which==1 -> H1 via superlevel
// (sublevel on -x, 4-conn, virtual -inf boundary node).
__global__ __launch_bounds__(NTH)
void pd_kernel(const float* __restrict__ x, float* __restrict__ out)
{
    const int blk   = blockIdx.x;
    const int s     = blk >> 1;
    const int which = blk & 1;
    const int tid   = threadIdx.x;
    const int lane  = tid & 63;
    const int M     = NPIX + which;

    __shared__ float vals[MMAX];
    __shared__ int   dA[MMAX];                  // descent ptr (ping); later minF/ddp
    __shared__ int   dB[MMAX];                  // ptr (pong); later dd2 (alive ancestor)
    __shared__ int   cmap[MMAX];                // root cell -> cid (own array: rank
                                                // overlaps jump pass 0, disjoint)
    __shared__ int   cido[MMAX];                // per-cell compact basin id
    __shared__ unsigned long long rootsU[BCAP]; // unsorted (valmono<<32)|cell
    __shared__ unsigned bval[BCAP];             // basin-min valmono per cid (= value rank)
    __shared__ unsigned hpool[2 * HSZ];         // hash key | hash val
    __shared__ unsigned cnt[NBUCK];             // bucket counters (separate; zeroed in B1)
    __shared__ unsigned long long e2[ECAP];     // unsorted edges; then SORTED; then sel keys
    __shared__ unsigned long long e3[ECAP];     // bucket-grouped scratch
    __shared__ unsigned long long mrec[PCAP];   // merge records (wmono<<32)|y (order free)
    __shared__ float pb[PCAP], pdd[PCAP];       // recorded pairs (output space)
    __shared__ int   rsel[NMAXP];               // output slot -> pair index
    __shared__ int   bcnt, scnt, npairs, np0g;
    __shared__ int   jflag[JMAXP + 1];
    __shared__ int   wtot[NTH / 64];

    unsigned* const hkey = hpool;               // hash: pk+1 (0 = empty)
    unsigned* const hval = hpool + HSZ;         // hash: min weight (monotone u32)

    // rank of ki among arr[0..N) (distinct keys; guarded loads -> no padding
    // required). Chunked: wave loads 64 keys coalesced, broadcasts via
    // readlane (unrolled -> constant lane), counts kjj < ki. No barriers.
    auto rankOf = [&](const unsigned long long* arr, int N,
                      unsigned long long ki) -> int {
        int rk = 0;
        int N64 = (N + 63) & ~63;
        for (int base = 0; base < N64; base += 64) {
            unsigned long long kj = (base + lane < N) ? arr[base + lane] : ~0ull;
            unsigned lo = (unsigned)kj, hi = (unsigned)(kj >> 32);
            #pragma unroll
            for (int t = 0; t < 64; ++t) {
                unsigned jlo = (unsigned)__builtin_amdgcn_readlane((int)lo, t);
                unsigned jhi = (unsigned)__builtin_amdgcn_readlane((int)hi, t);
                unsigned long long kjj = ((unsigned long long)jhi << 32) | jlo;
                rk += (kjj < ki) ? 1 : 0;
            }
        }
        return rk;
    };

    // ---- B1: init everything with no downstream ordering hazards ----
    if (tid == 0) { bcnt = 0; scnt = 0; npairs = 0; np0g = 0; }
    if (tid < JMAXP + 1) jflag[tid] = 0;
    for (int i = tid; i < HSZ; i += NTH) { hkey[i] = 0u; hval[i] = 0xFFFFFFFFu; }
    for (int i = tid; i < NBUCK; i += NTH) cnt[i] = 0u;
    for (int i = tid; i < NPIX; i += NTH) {
        float v = x[s * NPIX + i];
        vals[i] = which ? -v : v;
    }
    if (tid == 0 && which) vals[NPIX] = -INFINITY;
    __syncthreads();

    // ---- descent (lex-min over {self} U nbrs) + fused root collection ----
    // NTH >= M: exactly one cell per thread.
    unsigned long long rku = 0ull;
    int rc = 0;
    if (tid < M) {
        int i = tid;
        int best = i; float bv = vals[i];
        if (i < NPIX) {
            int nb[8];
            int K = get_nbrs(i, which, nb);
            for (int k = 0; k < K; ++k) {
                int n = nb[k]; if (n < 0) continue;
                float vn = vals[n];
                if (vn < bv || (vn == bv && n < best)) { bv = vn; best = n; }
            }
        }
        dA[i] = best;
        if (best == i) {
            rku = ((unsigned long long)f2mono(vals[i]) << 32) | (unsigned)i;
            rc = 1;
        }
    }
    {   // wave inclusive scan of rc -> one atomic per wave
        int sc = rc;
        #pragma unroll
        for (int d = 1; d < 64; d <<= 1) {
            int up = __shfl_up(sc, d, 64);
            if (lane >= d) sc += up;
        }
        int wtotal = __shfl(sc, 63, 64);
        int base = 0;
        if (lane == 0 && wtotal) base = atomicAdd(&bcnt, wtotal);
        base = __shfl(base, 0, 64);
        int off = base + sc - rc;
        if (rc && off < BCAP) rootsU[off] = rku;
    }
    __syncthreads();

    int B = bcnt; if (B > BCAP) B = BCAP;
    const int B64 = (B + 63) & ~63;

    // ---- pointer jumping: ping-pong doubling with exact early exit.
    //      cid rank-by-count OVERLAPS pass 0 (reads rootsU, writes cmap/bval
    //      only -- disjoint from dA/dB; waves 0-2 rank while others wait). ----
    int* rootArr = dA;
    {
        int* src = dA;
        int* dst = dB;
        for (int pass = 0; pass < JMAXP; ++pass) {
            bool changed = false;
            if (tid < M) {
                int q0 = src[tid];
                int q1 = src[q0];
                dst[tid] = q1;
                changed = (q1 != q0);
            }
            if (pass == 0) {
                for (int i = tid; i < B64; i += NTH) {
                    unsigned long long ki = (i < B) ? rootsU[i] : ~0ull;
                    int rk = rankOf(rootsU, B, ki);
                    if (i < B) {
                        cmap[(int)(ki & 0xFFFFFFFFull)] = rk;
                        bval[rk] = (unsigned)(ki >> 32);
                    }
                }
            }
            unsigned long long mk = __ballot(changed);
            if (lane == 0 && mk) jflag[pass] = 1;   // benign race: all store 1
            __syncthreads();
            rootArr = dst;
            if (!jflag[pass]) break;
            int* tmp = src; src = dst; dst = tmp;
        }
    }

    // ---- cid assignment ----
    if (tid < M) cido[tid] = cmap[rootArr[tid]];
    __syncthreads();
    // dA/dB dead from here -> reused by round-1 elimination:
    int* const minF = dA;        // [0..255] first-sorted-edge rank per basin
    int* const ddp  = dA + 256;  // [0..255] died-into pointer (identity = alive)
    int* const dd2  = dB;        // [0..255] alive ancestor after chase

    // ---- cross-basin edges -> hash dedup (min weight per basin pair) ----
    if (tid < NPIX) {
        int c = tid;
        float vc = vals[c];
        int bc = cido[c];
        int nb[8];
        int K = get_nbrs(c, which, nb);
        unsigned wm = f2mono(vc);
        for (int k = 0; k < K; ++k) {
            int n = nb[k]; if (n < 0) continue;
            float vn = vals[n];
            if (!(vn < vc || (vn == vc && n < c))) continue;  // emit from higher endpoint
            int bn = cido[n];
            if (bn == bc) continue;
            unsigned c0 = (unsigned)(bc < bn ? bc : bn);
            unsigned c1 = (unsigned)(bc < bn ? bn : bc);
            unsigned pk  = (c0 << 9) | c1;       // cids < 512 -> 18 bits
            unsigned key = pk + 1u;
            unsigned slot = (pk * 0x9E3779B1u) >> 21;  // 11-bit hash
            for (;;) {
                unsigned prev = atomicCAS(&hkey[slot], 0u, key);
                if (prev == 0u || prev == key) { atomicMin(&hval[slot], wm); break; }
                slot = (slot + 1) & HMASK;
            }
        }
    }
    __syncthreads();

    // ---- gather survivors + FUSED bucket count (cnt is separate storage) ----
    {
        unsigned k0 = hkey[tid], k1 = hkey[tid + NTH];
        unsigned v0 = hval[tid], v1 = hval[tid + NTH];
        int c = (k0 ? 1 : 0) + (k1 ? 1 : 0);
        int sc = c;
        #pragma unroll
        for (int d = 1; d < 64; d <<= 1) {
            int up = __shfl_up(sc, d, 64);
            if (lane >= d) sc += up;
        }
        int wtotal = __shfl(sc, 63, 64);
        int base = 0;
        if (lane == 0 && wtotal) base = atomicAdd(&scnt, wtotal);
        base = __shfl(base, 0, 64);
        int p = base + sc - c;
        if (k0) {
            e2[p] = ((unsigned long long)v0 << 18) | (unsigned long long)(k0 - 1u);
            atomicAdd(&cnt[v0 >> 21], 1u); ++p;
        }
        if (k1) {
            e2[p] = ((unsigned long long)v1 << 18) | (unsigned long long)(k1 - 1u);
            atomicAdd(&cnt[v1 >> 21], 1u); ++p;
        }
    }
    __syncthreads();
    const int S = scnt;                          // <= HSZ = ECAP, no overflow
    const int S64 = (S + 63) & ~63;
    const bool doR1 = (B <= 256) && (S > 0);

    // ---- exclusive prefix over NBUCK bins + e2 pad + round-1 array init ----
    {
        for (int i = S + tid; i < S64; i += NTH) e2[i] = ~0ull;  // Kruskal pad
        if (tid < 256) { minF[tid] = 0x7FFFFFFF; ddp[tid] = tid; }
        unsigned c[2]; int loc = 0;
        #pragma unroll
        for (int k2 = 0; k2 < 2; ++k2) { c[k2] = cnt[tid * 2 + k2]; loc += (int)c[k2]; }
        int scan = loc;
        #pragma unroll
        for (int d = 1; d < 64; d <<= 1) {
            int up = __shfl_up(scan, d, 64);
            if (lane >= d) scan += up;
        }
        int wid = tid >> 6;
        if (lane == 63) wtot[wid] = scan;
        __syncthreads();
        int wb = 0;
        for (int w2 = 0; w2 < wid; ++w2) wb += wtot[w2];   // each thread sums prefix
        int ex = wb + (scan - loc);
        #pragma unroll
        for (int k2 = 0; k2 < 2; ++k2) { cnt[tid * 2 + k2] = (unsigned)ex; ex += (int)c[k2]; }
    }
    __syncthreads();
    // ---- grouped scatter (atomic order; fixed by exact in-bucket rank) ----
    for (int i = tid; i < S; i += NTH) {
        unsigned long long k = e2[i];
        unsigned slot = atomicAdd(&cnt[(unsigned)(k >> 39)], 1u);
        e3[slot] = k;
    }
    __syncthreads();
    // ---- exact in-bucket rank (64-bit keys distinct -> deterministic) +
    //      FUSED round-1 minF (rk IS the sorted index) ----
    for (int i = tid; i < S; i += NTH) {
        unsigned long long ki = e3[i];
        int b = (int)(ki >> 39);
        int lo2 = (b == 0) ? 0 : (int)cnt[b - 1];
        int hi2 = (int)cnt[b];
        int rk = lo2;
        for (int j = lo2; j < hi2; ++j) rk += (e3[j] < ki) ? 1 : 0;
        e2[rk] = ki;
        if (doR1) {
            unsigned pk = (unsigned)ki & 0x3FFFFu;
            atomicMin(&minF[pk >> 9], rk);
            atomicMin(&minF[pk & 511u], rk);
        }
    }
    __syncthreads();

    // ---- ROUND-1 basin elimination (exact, parallel) ----
    // For basin y, its first sorted incident edge e=(y,z,w): if z older (z<y),
    // serial Kruskal provably kills y at e (comp(y)={y} there, since e is y's
    // min edge). Emit pair, mark y died->z. Residual Kruskal replays all edges
    // from pre-merged labels => identical pairing.
    if (doR1) {
        for (int y = tid; y < B; y += NTH) {
            int fi = minF[y];
            if (fi != 0x7FFFFFFF) {
                unsigned long long k = e2[fi];
                unsigned pk = (unsigned)k & 0x3FFFFu;
                int a = (int)(pk >> 9), bq = (int)(pk & 511u);
                int z = (a == y) ? bq : a;
                if (z < y) {   // partner older -> y dies here
                    unsigned wm = (unsigned)(k >> 18);
                    int slot = atomicAdd(&np0g, 1);
                    if (slot < PCAP)
                        mrec[slot] = ((unsigned long long)wm << 32) | (unsigned)y;
                    ddp[y] = z;
                }
            }
        }
    }
    __syncthreads();
    if (doR1) {
        for (int y = tid; y < 256; y += NTH) {   // chase died-into chain to alive root
            int r = ddp[y];
            int r2 = ddp[r];
            while (r2 != r) { r = r2; r2 = ddp[r]; }
            dd2[y] = r;
        }
    }
    __syncthreads();

    // ---- serial Kruskal on wave 0 (reads SORTED e2) ----
    // B <= 256 fast path: labels byte-PACKED, one 32-bit reg/lane
    // (byte j = label of basin j*64+lane), INITIALIZED from round-1 alive
    // ancestors. np starts at round-1's pair count.
    auto kruskalP = [&]() {
        unsigned pl = ((unsigned)dd2[tid]) | ((unsigned)dd2[64 + tid] << 8)
                    | ((unsigned)dd2[128 + tid] << 16) | ((unsigned)dd2[192 + tid] << 24);
        int np = np0g;
        const int target = B - 1;
        for (int base = 0; base < S && np < target; base += 64) {
            unsigned long long ecache = e2[base + tid];      // base mult of 64, tid<64
            unsigned eklo = (unsigned)ecache;
            unsigned ehiw = (unsigned)(ecache >> 32);
            unsigned pkL  = eklo & 0x3FFFFu;
            unsigned raaL = pkL >> 9, rbbL = pkL & 511u;     // < 256 here
            int bpa = __builtin_amdgcn_ds_bpermute((int)((raaL & 63u) << 2), (int)pl);
            int bpb = __builtin_amdgcn_ds_bpermute((int)((rbbL & 63u) << 2), (int)pl);
            unsigned la0 = ((unsigned)bpa >> ((raaL >> 6) * 8)) & 0xFFu;
            unsigned lb0 = ((unsigned)bpb >> ((rbbL >> 6) * 8)) & 0xFFu;
            bool isc = ((base + tid) < S) && (la0 != lb0);
            unsigned long long m = __ballot(isc);
            while (m != 0ull && np < target) {
                unsigned klo[4]; int lnt[4]; unsigned la[4], lb[4]; bool act[4];
                #pragma unroll
                for (int t = 0; t < 4; ++t) {
                    act[t] = (m != 0ull);
                    int ln = act[t] ? (int)__builtin_ctzll(m) : 0;
                    if (act[t]) m &= (m - 1ull);
                    lnt[t] = ln;
                    klo[t] = (unsigned)__builtin_amdgcn_readlane((int)eklo, ln);
                    unsigned pk  = klo[t] & 0x3FFFFu;
                    unsigned raa = pk >> 9, rbb = pk & 511u;  // uniform scalars
                    unsigned kra = (unsigned)__builtin_amdgcn_readlane((int)pl, (int)(raa & 63u));
                    unsigned krb = (unsigned)__builtin_amdgcn_readlane((int)pl, (int)(rbb & 63u));
                    la[t] = (kra >> ((raa >> 6) * 8)) & 0xFFu;   // uniform -> SALU
                    lb[t] = (krb >> ((rbb >> 6) * 8)) & 0xFFu;
                    if (!act[t]) { la[t] = 0; lb[t] = 0; }       // no-op slot
                }
                unsigned ys[4], es[4];
                #pragma unroll
                for (int t = 0; t < 4; ++t) {
                    unsigned A = la[t], Bv = lb[t];
                    #pragma unroll
                    for (int k = 0; k < t; ++k) {
                        A  = (A  == ys[k]) ? es[k] : A;
                        Bv = (Bv == ys[k]) ? es[k] : Bv;
                    }
                    unsigned mn = A < Bv ? A : Bv;
                    unsigned mx = A ^ Bv ^ mn;
                    es[t] = mn;
                    ys[t] = (A != Bv) ? mx : 0xFFFFFFFFu;   // sentinel: no merge
                }
                #pragma unroll
                for (int t = 0; t < 4; ++t) {
                    if (ys[t] != 0xFFFFFFFFu) {
                        unsigned khit = (unsigned)__builtin_amdgcn_readlane(
                            (int)ehiw, lnt[t]);
                        unsigned w = (klo[t] >> 18) | (khit << 14);
                        if (tid == 0 && np < PCAP)
                            mrec[np] = ((unsigned long long)w << 32)
                                     | (unsigned long long)ys[t];
                        ++np;
                        // packed byte replace: bytes of pl equal to y -> e
                        unsigned yr  = ys[t] * 0x01010101u;
                        unsigned xr  = (ys[t] ^ es[t]) * 0x01010101u;
                        unsigned mm  = pl ^ yr;                          // 0-byte = match
                        unsigned nz  = ((mm & 0x7F7F7F7Fu) + 0x7F7F7F7Fu) | mm;
                        unsigned tz  = ~nz & 0x80808080u;                // 0x80 at matches
                        unsigned msk = tz | (tz - (tz >> 7));            // 0xFF at matches
                        pl ^= (xr & msk);
                    }
                }
            }
        }
        if (tid == 0) npairs = (np < PCAP) ? np : PCAP;
    };

    // fallback for 256 < B <= 512: striped labels in 8 regs (no round-1)
    auto kruskal = [&](auto icreg) {
        constexpr int NREG = decltype(icreg)::v;
        int lab[NREG];
        #pragma unroll
        for (int r = 0; r < NREG; ++r) lab[r] = r * 64 + tid;
        int np = 0;
        const int target = B - 1;
        for (int base = 0; base < S && np < target; base += 64) {
            unsigned long long ecache = e2[base + tid];
            unsigned eklo = (unsigned)ecache;
            unsigned ehiw = (unsigned)(ecache >> 32);
            unsigned pkL  = eklo & 0x3FFFFu;
            unsigned raaL = pkL >> 9, rbbL = pkL & 511u;
            int bpa[NREG], bpb[NREG];
            int aA = (int)((raaL & 63u) << 2);
            int aB = (int)((rbbL & 63u) << 2);
            #pragma unroll
            for (int r = 0; r < NREG; ++r) {
                bpa[r] = __builtin_amdgcn_ds_bpermute(aA, lab[r]);
                bpb[r] = __builtin_amdgcn_ds_bpermute(aB, lab[r]);
            }
            int la0, lb0;
            {
                unsigned sA = raaL >> 6, sB = rbbL >> 6;
                int x0 = (sA & 1) ? bpa[1] : bpa[0];
                int x1 = (sA & 1) ? bpa[3] : bpa[2];
                int x2 = (sA & 1) ? bpa[5] : bpa[4];
                int x3 = (sA & 1) ? bpa[7] : bpa[6];
                int x4 = (sA & 2) ? x1 : x0;
                int x5 = (sA & 2) ? x3 : x2;
                la0 = (sA & 4) ? x5 : x4;
                int y0 = (sB & 1) ? bpb[1] : bpb[0];
                int y1 = (sB & 1) ? bpb[3] : bpb[2];
                int y2 = (sB & 1) ? bpb[5] : bpb[4];
                int y3 = (sB & 1) ? bpb[7] : bpb[6];
                int y4 = (sB & 2) ? y1 : y0;
                int y5 = (sB & 2) ? y3 : y2;
                lb0 = (sB & 4) ? y5 : y4;
            }
            bool isc = ((base + tid) < S) && (la0 != lb0);
            unsigned long long m = __ballot(isc);
            while (m != 0ull && np < target) {
                unsigned klo[4]; int lnt[4], la[4], lb[4]; bool act[4];
                #pragma unroll
                for (int t = 0; t < 4; ++t) {
                    act[t] = (m != 0ull);
                    int ln = act[t] ? (int)__builtin_ctzll(m) : 0;
                    if (act[t]) m &= (m - 1ull);
                    lnt[t] = ln;
                    klo[t] = (unsigned)__builtin_amdgcn_readlane((int)eklo, ln);
                    unsigned pk  = klo[t] & 0x3FFFFu;
                    unsigned raa = pk >> 9, rbb = pk & 511u;
                    int sa = (int)(raa >> 6), sb = (int)(rbb >> 6);
                    asm volatile("" : "+v"(sa), "+v"(sb));   // force cndmask tree
                    int a1 = (sa & 1) ? lab[1] : lab[0];
                    int b1 = (sa & 1) ? lab[3] : lab[2];
                    int c1 = (sa & 1) ? lab[5] : lab[4];
                    int d1 = (sa & 1) ? lab[7] : lab[6];
                    int e1 = (sa & 2) ? b1 : a1;
                    int f1 = (sa & 2) ? d1 : c1;
                    int g1 = (sa & 4) ? f1 : e1;
                    int a2 = (sb & 1) ? lab[1] : lab[0];
                    int b2 = (sb & 1) ? lab[3] : lab[2];
                    int c2 = (sb & 1) ? lab[5] : lab[4];
                    int d2 = (sb & 1) ? lab[7] : lab[6];
                    int e2v = (sb & 2) ? b2 : a2;
                    int f2 = (sb & 2) ? d2 : c2;
                    int g2 = (sb & 4) ? f2 : e2v;
                    la[t] = __builtin_amdgcn_readlane(g1, (int)(raa & 63u));
                    lb[t] = __builtin_amdgcn_readlane(g2, (int)(rbb & 63u));
                    if (!act[t]) { la[t] = 0; lb[t] = 0; }
                }
                int ys[4], es[4];
                #pragma unroll
                for (int t = 0; t < 4; ++t) {
                    int A = la[t], Bv = lb[t];
                    #pragma unroll
                    for (int k = 0; k < t; ++k) {
                        A  = (A  == ys[k]) ? es[k] : A;
                        Bv = (Bv == ys[k]) ? es[k] : Bv;
                    }
                    int mn = A < Bv ? A : Bv;
                    int mx = A ^ Bv ^ mn;
                    es[t] = mn;
                    ys[t] = (A != Bv) ? mx : -1;
                }
                #pragma unroll
                for (int t = 0; t < 4; ++t) {
                    if (ys[t] >= 0) {
                        unsigned khit = (unsigned)__builtin_amdgcn_readlane(
                            (int)ehiw, lnt[t]);
                        unsigned w = (klo[t] >> 18) | (khit << 14);
                        if (tid == 0 && np < PCAP)
                            mrec[np] = ((unsigned long long)w << 32) | (unsigned)ys[t];
                        ++np;
                        #pragma unroll
                        for (int r = 0; r < NREG; ++r)
                            lab[r] = (lab[r] == ys[t]) ? es[t] : lab[r];
                    }
                }
            }
        }
        if (tid == 0) npairs = (np < PCAP) ? np : PCAP;
    };

    if (tid < 64 && S > 0) {
        if (B <= 256) kruskalP();
        else          kruskal(IC<8>{});
    }
    __syncthreads();
    const int P = npairs;
    const int P64 = (P + 63) & ~63;

    // ---- materialize pairs + build selection keys (pers desc, idx asc) ----
    for (int i = tid; i < P64; i += NTH) {
        unsigned long long kk2 = ~0ull;
        if (i < P) {
            unsigned long long m = mrec[i];
            int y = (int)(m & 0xFFFFFFFFull);
            float w  = mono2f((unsigned)(m >> 32));
            float bf = mono2f(bval[y]);
            float b, d;
            if (which == 0) { b = bf; d = w; }
            else            { b = -w; d = -bf; }
            pb[i] = b; pdd[i] = d;
            unsigned pm = __float_as_uint(d - b);   // pers > 0 -> monotone bits
            kk2 = ((unsigned long long)(~pm) << 32) | (unsigned)i;
        }
        e2[i] = kk2;
    }
    if (tid < NMAXP) rsel[tid] = -1;
    __syncthreads();

    // ---- top-NMAXP by rank-by-count ----
    const int off = (which == 0) ? 1 : 0;          // H0 slot 0 = essential pair
    for (int i = tid; i < P64; i += NTH) {
        unsigned long long ki = e2[i];
        int rk = rankOf(e2, P64, ki);
        if (i < P && rk < NMAXP - off) rsel[rk + off] = i;
    }
    __syncthreads();

    // ---- write diagram: [32, 2, 100, 2] ----
    float* o = out + (size_t)blk * NMAXP * 2;
    if (tid < NMAXP) {
        float b = 0.f, d = 0.f;
        if (which == 0 && tid == 0) { b = mono2f(bval[0]); d = ESS_DEATH; }
        else {
            int q = rsel[tid];
            if (q >= 0) { b = pb[q]; d = pdd[q]; }
        }
        o[tid * 2]     = b;
        o[tid * 2 + 1] = d;
    }
}

extern "C" void kernel_launch(void* const* d_in, const int* in_sizes, int n_in,
                              void* d_out, int out_size, void* d_ws, size_t ws_size,
                              hipStream_t stream) {
    (void)in_sizes; (void)n_in; (void)out_size; (void)d_ws; (void)ws_size;
    const float* x = (const float*)d_in[0];
    float* out = (float*)d_out;
    pd_kernel<<<dim3(64), dim3(NTH), 0, stream>>>(x, out);
}